// Round 4
// baseline (318.690 us; speedup 1.0000x reference)
//
#include <hip/hip_runtime.h>

#define NTIPS 512
#define DIM   510                     // internal nodes = ntips - 2
#define TOTAL 1022
#define BS    64
#define ITERS 50
#define SLABF 8                       // features per workgroup slab
#define NSLAB 64
#define NWG   (BS * NSLAB)            // 4096 workgroups
#define NPART ((size_t)ITERS * BS * NSLAB)

#define ROWEL 8                       // u16 elems per row-slab (16 B)
#define XSEC   (DIM * ROWEL)          // evolving X section = 4080 u16
#define ONEOFF XSEC                   // 8 one-hot const rows
#define ZROW   (XSEC + 8 * ROWEL)     // all-zero const row
#define BSTRIDE (XSEC + 9 * ROWEL)    // u16 per LDS buffer = 4152
#define BUFB   (BSTRIDE * 2)          // bytes per LDS buffer = 8304

#define XB ((size_t)BS * DIM * NTIPS) // u16 elems per snapshot slot
#define SLOTB (XB * 2)                // bytes per snapshot slot (33.4 MB)
#define WGB  (DIM * ROWEL * 2)        // bytes per WG region in a slot = 8160

typedef unsigned short u16;
typedef unsigned int   u32;
typedef float f32x2 __attribute__((ext_vector_type(2)));

// bf16 RNE helpers
__device__ __forceinline__ u16 f2bf(float x) {
    u32 u = __float_as_uint(x);
    return (u16)((u + 0x7FFFu + ((u >> 16) & 1u)) >> 16);
}
__device__ __forceinline__ float bf2f(u16 h) { return __uint_as_float(((u32)h) << 16); }
__device__ __forceinline__ float bflo(u32 p) { return __uint_as_float(p << 16); }
__device__ __forceinline__ float bfhi(u32 p) { return __uint_as_float(p & 0xFFFF0000u); }
__device__ __forceinline__ f32x2 unpk(u32 p) {
    f32x2 r; r.x = bflo(p); r.y = bfhi(p); return r;   // (lo elem, hi elem)
}

#if defined(__has_builtin)
#  if __has_builtin(__builtin_amdgcn_cvt_pk_bf16_f32)
#    define HAVE_PKBF 1
#  endif
#endif
#ifdef HAVE_PKBF
typedef __bf16 bf16x2 __attribute__((ext_vector_type(2)));
__device__ __forceinline__ u32 pkbf(float a, float b) {   // lo=a, hi=b, RNE
    bf16x2 r = __builtin_amdgcn_cvt_pk_bf16_f32(a, b);
    return __builtin_bit_cast(u32, r);
}
#else
__device__ __forceinline__ u32 pkbf(float a, float b) {
    return (u32)f2bf(a) | ((u32)f2bf(b) << 16);
}
#endif

// correctly-rounded f32 division by 3 (Markstein mul+2fma) — R2/R3-validated
__device__ __forceinline__ f32x2 div3v(f32x2 x) {
    const float C = 0x1.555556p-2f;               // RN(1/3)
    f32x2 q0, r, q;
    q0.x = x.x * C;             q0.y = x.y * C;
    r.x = fmaf(-3.f, q0.x, x.x); r.y = fmaf(-3.f, q0.y, x.y);
    q.x = fmaf(r.x, C, q0.x);    q.y = fmaf(r.y, C, q0.y);
    return q;
}

// LDS-only barrier: waits LDS ops, does NOT drain vmcnt (snapshot stores
// stay in flight across steps). R3-validated.
__device__ __forceinline__ void barrier_lds_only() {
    __builtin_amdgcn_sched_barrier(0);
    asm volatile("s_waitcnt lgkmcnt(0)" ::: "memory");
    __builtin_amdgcn_s_barrier();
    __builtin_amdgcn_sched_barrier(0);
}

// register-resident gather offsets (BYTE units, LDS-buffer-relative)
__device__ __forceinline__ void make_offsets(const int* __restrict__ edge,
        int b, int sl, int rg, int lbyte, int nr, u32 offB[4][3]) {
    #pragma unroll
    for (int k = 0; k < 4; ++k) if (k < nr) {
        const int i = rg + 128 * k;
        const int* ep = edge + ((size_t)b * TOTAL + NTIPS + i) * 3;
        #pragma unroll
        for (int t = 0; t < 3; ++t) {
            const int e = ep[t];
            u32 off;
            if (e >= NTIPS)          off = (u32)((e - NTIPS) * ROWEL);
            else if ((e >> 3) == sl) off = (u32)(ONEOFF + (e & 7) * ROWEL);
            else                     off = (u32)ZROW;
            offB[k][t] = off * 2u + (u32)lbyte;
        }
    }
}

__device__ __forceinline__ void init_const_rows(u16* X, int tid) {
    for (int j = tid; j < 9 * ROWEL; j += 256) {
        const int row = j >> 3, col = j & 7;
        const u16 v = (row == col) ? (u16)0x3F80 : (u16)0;  // row 8 = zeros
        X[ONEOFF + j] = v;
        X[BSTRIDE + ONEOFF + j] = v;
    }
}

// ---------------------------------------------------------------------------
// chunk q: W steps (sBeg..sBeg+W-1). 8-feature slabs -> 16.6 KB LDS ->
// 8 WG/CU (2x R3 occupancy). Snapshots EVERY step s into slot s&MASK,
// slab-major (coalesced 512 B/wave). No fences/atomics (R2 lesson).
// Slot-safety: each step writes slot s&MASK exactly once; a chunk reload
// only needs the PREVIOUS chunk's last step -> any W<=MASK+1 works.
// ---------------------------------------------------------------------------
template<int W, int MASK>
__global__ __launch_bounds__(256, 8) void chunk_kernel(
        const int* __restrict__ edge, float* __restrict__ partials,
        const int* __restrict__ ctrl, u16* __restrict__ slots, int q, int sBeg) {
    if (q >= 2 && ctrl[2] != 0) return;          // converged: skip

    __shared__ u16 X[2 * BSTRIDE];
    __shared__ float redL[2][4];

    const int wg = blockIdx.x, b = wg >> 6, sl = wg & 63;
    const int tid = threadIdx.x, rg = tid >> 1;  // row group 0..127
    const int lbyte = (tid & 1) << 3;            // byte offset in row (8 B)
    const int nr = (rg < 126) ? 4 : 3;           // rows rg+128k < 510
    char* Xc = reinterpret_cast<char*>(X);
    const u32 r0b = (u32)(rg * 16 + lbyte);      // own-row LDS byte base

    u32 offB[4][3];
    make_offsets(edge, b, sl, rg, lbyte, nr, offB);

    // slab-major global byte offsets of own rows within one snapshot slot
    u32 rowByte[4];
    #pragma unroll
    for (int k = 0; k < 4; ++k)
        rowByte[k] = (u32)wg * (u32)WGB + (u32)((rg + 128 * k) * 16) + (u32)lbyte;

    if (q == 1) {
        for (int j = tid; j < XSEC / 2; j += 256)
            reinterpret_cast<u32*>(X)[j] = 0x3B003B00u;   // X0 = bf16(1/512)
    } else {
        const char* src0 = reinterpret_cast<const char*>(slots)
                         + (size_t)((sBeg - 1) & MASK) * SLOTB;
        #pragma unroll
        for (int k = 0; k < 4; ++k) if (k < nr)
            *reinterpret_cast<uint2*>(Xc + r0b + (k << 11)) =
                *reinterpret_cast<const uint2*>(src0 + rowByte[k]);
    }
    init_const_rows(X, tid);

    // old-row values in registers (own rows, written by self — no barrier)
    f32x2 old01[4], old23[4];
    #pragma unroll
    for (int k = 0; k < 4; ++k) if (k < nr) {
        const uint2 ov = *reinterpret_cast<const uint2*>(Xc + r0b + (k << 11));
        old01[k] = unpk(ov.x); old23[k] = unpk(ov.y);
    }
    __syncthreads();

    #pragma unroll
    for (int u = 0; u < W; ++u) {
        const int s = sBeg + u;
        const int srcB = (u & 1) ? BUFB : 0;     // compile-time after unroll
        const int dstB = ((u + 1) & 1) ? BUFB : 0;
        char* slotC = reinterpret_cast<char*>(slots) + (size_t)(s & MASK) * SLOTB;
        float dacc = 0.f;
        #pragma unroll
        for (int k = 0; k < 4; ++k) if (k < nr) {
            const uint2 g0 = *reinterpret_cast<const uint2*>(Xc + offB[k][0] + srcB);
            const uint2 g1 = *reinterpret_cast<const uint2*>(Xc + offB[k][1] + srcB);
            const uint2 g2 = *reinterpret_cast<const uint2*>(Xc + offB[k][2] + srcB);
            const f32x2 a01 = (unpk(g0.x) + unpk(g1.x)) + unpk(g2.x);
            const f32x2 a23 = (unpk(g0.y) + unpk(g1.y)) + unpk(g2.y);
            const f32x2 q01 = div3v(a01), q23 = div3v(a23);
            uint2 nv;
            nv.x = pkbf(q01.x, q01.y);
            nv.y = pkbf(q23.x, q23.y);
            *reinterpret_cast<uint2*>(Xc + r0b + ((k << 11) + dstB)) = nv;
            *reinterpret_cast<uint2*>(slotC + rowByte[k]) = nv;   // coalesced
            const f32x2 n01 = unpk(nv.x), n23 = unpk(nv.y);
            const f32x2 d01v = n01 - old01[k];
            const f32x2 d23v = n23 - old23[k];
            const u32 d01 = pkbf(d01v.x, d01v.y);
            const u32 d23 = pkbf(d23v.x, d23v.y);
            dacc += fabsf(bflo(d01));
            dacc += fabsf(bfhi(d01));
            dacc += fabsf(bflo(d23));
            dacc += fabsf(bfhi(d23));
            old01[k] = n01; old23[k] = n23;
        }
        #pragma unroll
        for (int off = 32; off > 0; off >>= 1) dacc += __shfl_down(dacc, off);
        if ((tid & 63) == 0) redL[u & 1][tid >> 6] = dacc;
        barrier_lds_only();                      // LDS wait only, no vm drain
        if (tid == 0) {
            const float dtot = ((redL[u & 1][0] + redL[u & 1][1])
                                + redL[u & 1][2]) + redL[u & 1][3];
            partials[((size_t)(s - 1) * BS + b) * NSLAB + sl] = dtot;
        }
    }
}

// ---------------------------------------------------------------------------
// findS (separate dispatch — visibility via kernel boundary, no fences).
// ---------------------------------------------------------------------------
__global__ void findS_kernel(const float* __restrict__ partials,
                             int* __restrict__ ctrl, int smax) {
    if (ctrl[2] != 0) return;
    const int lane = threadIdx.x;                // 64 lanes = trees
    const float tol_bf = bf2f(f2bf(1e-5f));
    int S = -1;
    for (int s = 1; s <= smax; ++s) {
        const float* p = partials + ((size_t)(s - 1) * BS + lane) * NSLAB;
        float t = 0.f;
        #pragma unroll
        for (int k = 0; k < NSLAB; ++k) t += p[k];
        const float lnorm = bf2f(f2bf(t / 261120.0f));
        if (__ballot(lnorm > tol_bf) == 0ULL) { S = s; break; }
    }
    if (S < 0 && smax == ITERS) S = ITERS;       // cap at MAX_ITERS
    if (lane == 0 && S > 0) { ctrl[0] = S; ctrl[2] = 1; }
}

// ---------------------------------------------------------------------------
// copyFinal: slot S&3 -> finalX (ws). Used only when slots live in d_out.
// ---------------------------------------------------------------------------
__global__ __launch_bounds__(256) void copyfinal_kernel(
        const int* __restrict__ ctrl, const u16* __restrict__ slots,
        u16* __restrict__ finalX) {
    const int S = ctrl[0];
    const uint4* src = reinterpret_cast<const uint4*>(slots + (size_t)(S & 3) * XB);
    uint4* dst = reinterpret_cast<uint4*>(finalX);
    const size_t n = XB / 8;
    for (size_t i = (size_t)blockIdx.x * 256 + threadIdx.x; i < n;
         i += (size_t)gridDim.x * 256)
        dst[i] = src[i];
}

// ---------------------------------------------------------------------------
// convert: d_out fp32 = [identity ; f32(bf16 X_S)] per batch.
// Source slab-major [wg = b*64+sl][row][8]. mask>=0 -> slot ctrl[0]&mask.
// thread tid owns slab tid (8 feats) of its row — one 16-B read.
// ---------------------------------------------------------------------------
__global__ __launch_bounds__(64) void convert_kernel(
        const u16* __restrict__ base, const int* __restrict__ ctrl, int mask,
        float* __restrict__ out) {
    const int r = blockIdx.x;                    // 0..1021
    const int b = blockIdx.y;
    const int f0 = threadIdx.x << 3;             // 8 floats per thread
    float4 lo, hi;
    if (r < NTIPS) {
        lo.x = (r == f0 + 0) ? 1.f : 0.f;
        lo.y = (r == f0 + 1) ? 1.f : 0.f;
        lo.z = (r == f0 + 2) ? 1.f : 0.f;
        lo.w = (r == f0 + 3) ? 1.f : 0.f;
        hi.x = (r == f0 + 4) ? 1.f : 0.f;
        hi.y = (r == f0 + 5) ? 1.f : 0.f;
        hi.z = (r == f0 + 6) ? 1.f : 0.f;
        hi.w = (r == f0 + 7) ? 1.f : 0.f;
    } else {
        const u16* src = base + (mask >= 0 ? (size_t)(ctrl[0] & mask) * XB
                                           : (size_t)0);
        const u16* row = src + (((size_t)b * NSLAB + threadIdx.x) * DIM
                                + (r - NTIPS)) * ROWEL;
        const ushort4 a = *reinterpret_cast<const ushort4*>(row);
        const ushort4 c = *reinterpret_cast<const ushort4*>(row + 4);
        lo.x = bf2f(a.x); lo.y = bf2f(a.y); lo.z = bf2f(a.z); lo.w = bf2f(a.w);
        hi.x = bf2f(c.x); hi.y = bf2f(c.y); hi.z = bf2f(c.z); hi.w = bf2f(c.w);
    }
    float* drow = out + ((size_t)b * TOTAL + r) * NTIPS + f0;
    *reinterpret_cast<float4*>(drow)     = lo;
    *reinterpret_cast<float4*>(drow + 4) = hi;
}

extern "C" void kernel_launch(void* const* d_in, const int* in_sizes, int n_in,
                              void* d_out, int out_size, void* d_ws, size_t ws_size,
                              hipStream_t stream) {
    const int* edge = (const int*)d_in[1];       // (BS, TOTAL, 3) int32
    float* out = (float*)d_out;
    const size_t partB = NPART * sizeof(float);

    if (ws_size >= 8 * SLOTB + partB + 256) {
        // ---- 8-slot ring in ws. Zero-overshoot for S<=12:
        // W4 x3 (steps 1-12), then W8 x4 (13-44), W6 (45-50). --------------
        u16*   slots    = (u16*)d_ws;
        float* partials = (float*)((char*)d_ws + 8 * SLOTB);
        int*   ctrl     = (int*)((char*)partials + partB);
        hipMemsetAsync(ctrl, 0, 4 * sizeof(int), stream);
        for (int q = 1; q <= 3; ++q) {
            chunk_kernel<4, 7><<<NWG, 256, 0, stream>>>(edge, partials, ctrl,
                                                        slots, q, 4 * q - 3);
            findS_kernel<<<1, 64, 0, stream>>>(partials, ctrl, 4 * q);
        }
        for (int q = 4; q <= 7; ++q) {
            chunk_kernel<8, 7><<<NWG, 256, 0, stream>>>(edge, partials, ctrl,
                                                        slots, q,
                                                        13 + 8 * (q - 4));
            findS_kernel<<<1, 64, 0, stream>>>(partials, ctrl, 20 + 8 * (q - 4));
        }
        chunk_kernel<6, 7><<<NWG, 256, 0, stream>>>(edge, partials, ctrl,
                                                    slots, 8, 45);
        findS_kernel<<<1, 64, 0, stream>>>(partials, ctrl, 50);
        convert_kernel<<<dim3(TOTAL, BS), 64, 0, stream>>>(slots, ctrl, 7, out);
    } else if (ws_size >= 4 * SLOTB + partB + 256) {
        // ---- 4-slot ring in ws: 12 x W4 + W2 ------------------------------
        u16*   slots    = (u16*)d_ws;
        float* partials = (float*)((char*)d_ws + 4 * SLOTB);
        int*   ctrl     = (int*)((char*)partials + partB);
        hipMemsetAsync(ctrl, 0, 4 * sizeof(int), stream);
        for (int q = 1; q <= 12; ++q) {
            chunk_kernel<4, 3><<<NWG, 256, 0, stream>>>(edge, partials, ctrl,
                                                        slots, q, 4 * q - 3);
            findS_kernel<<<1, 64, 0, stream>>>(partials, ctrl, 4 * q);
        }
        chunk_kernel<2, 3><<<NWG, 256, 0, stream>>>(edge, partials, ctrl,
                                                    slots, 13, 49);
        findS_kernel<<<1, 64, 0, stream>>>(partials, ctrl, 50);
        convert_kernel<<<dim3(TOTAL, BS), 64, 0, stream>>>(slots, ctrl, 3, out);
    } else {
        // ---- fallback: 4 slots in d_out, finalX in ws ---------------------
        u16*   slots    = (u16*)d_out;
        u16*   finalX   = (u16*)d_ws;
        float* partials = (float*)((char*)d_ws + SLOTB);
        int*   ctrl     = (int*)((char*)partials + partB);
        hipMemsetAsync(ctrl, 0, 4 * sizeof(int), stream);
        for (int q = 1; q <= 12; ++q) {
            chunk_kernel<4, 3><<<NWG, 256, 0, stream>>>(edge, partials, ctrl,
                                                        slots, q, 4 * q - 3);
            findS_kernel<<<1, 64, 0, stream>>>(partials, ctrl, 4 * q);
        }
        chunk_kernel<2, 3><<<NWG, 256, 0, stream>>>(edge, partials, ctrl,
                                                    slots, 13, 49);
        findS_kernel<<<1, 64, 0, stream>>>(partials, ctrl, 50);
        copyfinal_kernel<<<2048, 256, 0, stream>>>(ctrl, slots, finalX);
        convert_kernel<<<dim3(TOTAL, BS), 64, 0, stream>>>(finalX, ctrl, -1, out);
    }
}

// Round 5
// 318.468 us; speedup vs baseline: 1.0007x; 1.0007x over previous
//
#include <hip/hip_runtime.h>

// ---- problem geometry ----
#define NTIPS 512
#define DIM   510                     // internal nodes = ntips - 2
#define TOTAL 1022
#define BS    64
#define ITERS 50

// ---- persistent-kernel config: 16-feat slabs, single-buffered LDS ----
#define NSLAB2 32
#define NWG2   (BS * NSLAB2)          // 2048 workgroups == machine capacity
#define ROWEL2 16                     // u16 per row-slab (32 B)
#define XSEC2  (DIM * ROWEL2)         // 8160 u16
#define ONE2   XSEC2                  // 16 one-hot const rows
#define ZROW2  (XSEC2 + 16 * ROWEL2)  // all-zero const row
#define BSTR2  (XSEC2 + 17 * ROWEL2)  // 8432 u16 = 16864 B (single buffer)
#define NPART2 ((size_t)ITERS * NWG2)

// ---- R4 fallback config (proven path) ----
#define SLABF 8
#define NSLAB 64
#define NWG   (BS * NSLAB)            // 4096 workgroups
#define NPART ((size_t)ITERS * BS * NSLAB)
#define ROWEL 8
#define XSEC   (DIM * ROWEL)
#define ONEOFF XSEC
#define ZROW   (XSEC + 8 * ROWEL)
#define BSTRIDE (XSEC + 9 * ROWEL)
#define BUFB   (BSTRIDE * 2)
#define XB ((size_t)BS * DIM * NTIPS)
#define SLOTB (XB * 2)
#define WGB  (DIM * ROWEL * 2)

typedef unsigned short u16;
typedef unsigned int   u32;
typedef float f32x2 __attribute__((ext_vector_type(2)));

// bf16 RNE helpers
__device__ __forceinline__ u16 f2bf(float x) {
    u32 u = __float_as_uint(x);
    return (u16)((u + 0x7FFFu + ((u >> 16) & 1u)) >> 16);
}
__device__ __forceinline__ float bf2f(u16 h) { return __uint_as_float(((u32)h) << 16); }
__device__ __forceinline__ float bflo(u32 p) { return __uint_as_float(p << 16); }
__device__ __forceinline__ float bfhi(u32 p) { return __uint_as_float(p & 0xFFFF0000u); }
__device__ __forceinline__ f32x2 unpk(u32 p) {
    f32x2 r; r.x = bflo(p); r.y = bfhi(p); return r;
}

#if defined(__has_builtin)
#  if __has_builtin(__builtin_amdgcn_cvt_pk_bf16_f32)
#    define HAVE_PKBF 1
#  endif
#endif
#ifdef HAVE_PKBF
typedef __bf16 bf16x2 __attribute__((ext_vector_type(2)));
__device__ __forceinline__ u32 pkbf(float a, float b) {   // lo=a, hi=b, RNE
    bf16x2 r = __builtin_amdgcn_cvt_pk_bf16_f32(a, b);
    return __builtin_bit_cast(u32, r);
}
#else
__device__ __forceinline__ u32 pkbf(float a, float b) {
    return (u32)f2bf(a) | ((u32)f2bf(b) << 16);
}
#endif

// correctly-rounded f32 division by 3 (Markstein mul+2fma) — R2/R3/R4-validated
__device__ __forceinline__ f32x2 div3v(f32x2 x) {
    const float C = 0x1.555556p-2f;               // RN(1/3)
    f32x2 q0, r, q;
    q0.x = x.x * C;             q0.y = x.y * C;
    r.x = fmaf(-3.f, q0.x, x.x); r.y = fmaf(-3.f, q0.y, x.y);
    q.x = fmaf(r.x, C, q0.x);    q.y = fmaf(r.y, C, q0.y);
    return q;
}

// one packed element pair: ((g0+g1)+g2)/3, pack, delta vs own — validated chain
__device__ __forceinline__ u32 stepElem(u32 a0, u32 a1, u32 a2, u32 own,
                                        float& dacc) {
    const f32x2 a = (unpk(a0) + unpk(a1)) + unpk(a2);
    const f32x2 q = div3v(a);
    const u32 nv = pkbf(q.x, q.y);
    const f32x2 n = unpk(nv), o = unpk(own);
    const u32 dd = pkbf(n.x - o.x, n.y - o.y);
    dacc += fabsf(bflo(dd));
    dacc += fabsf(bfhi(dd));
    return nv;
}

// ===========================================================================
// PERSISTENT KERNEL — all S steps in one launch.
// 2048 WGs (=capacity at 8 WG/CU via __launch_bounds__(256,8)), 16-feat slab
// per WG, X single-buffered in LDS. Per step:
//   phase A : all LDS reads (3 gathers + own-old) -> nv in regs + dacc
//   epoch barrier (fused with convergence check, zero decision lag):
//     tid0: release-store partial, release-store arrive[wg]=s
//     wg0 : poll arrive[]==s (2048 independent words — no atomic contention),
//           then run the EXACT validated findS sum/ballot, release gate[s]
//     all : spin gate[s] (read-only one line), decision in bit1
//   exit (d or s==50): X_S == nv regs -> write fp32 output fused (no convert)
//   phase B : write nv -> LDS, __syncthreads
// No fences besides scoped atomics (R1/R2 lesson: no L2-writeback storms —
// dirty global data per WG per step is 8 bytes).
// ===========================================================================
__global__ __launch_bounds__(256, 8) void persist_kernel(
        const int* __restrict__ edge, float* __restrict__ partials,
        unsigned* __restrict__ arrive, int* __restrict__ gate,
        float* __restrict__ out) {
    __shared__ u16 X[BSTR2];
    __shared__ float redL[4];
    __shared__ int fbc;

    const int wg = blockIdx.x, b = wg >> 5, sl = wg & 31;
    const int tid = threadIdx.x;
    const int rg = tid >> 1;                 // row group 0..127
    const int h  = tid & 1;                  // feature half (8 feats = 16 B)
    const int lbyte = h << 4;
    const int nr = (rg < 126) ? 4 : 3;       // rows rg+128k < 510
    char* Xc = reinterpret_cast<char*>(X);
    const u32 r0b = (u32)(rg * 32 + lbyte);  // own-row LDS byte base (+k<<12)

    // gather offsets (bytes, LDS-relative)
    u32 offB[4][3];
    #pragma unroll
    for (int k = 0; k < 4; ++k) if (k < nr) {
        const int i = rg + (k << 7);
        const int* ep = edge + ((size_t)b * TOTAL + NTIPS + i) * 3;
        #pragma unroll
        for (int t = 0; t < 3; ++t) {
            const int e = ep[t];
            u32 off;
            if (e >= NTIPS)          off = (u32)((e - NTIPS) * ROWEL2);
            else if ((e >> 4) == sl) off = (u32)(ONE2 + (e & 15) * ROWEL2);
            else                     off = (u32)ZROW2;
            offB[k][t] = off * 2u + (u32)lbyte;
        }
    }

    // X0 = bf16(1/512); const rows
    for (int j = tid; j < XSEC2 / 2; j += 256)
        reinterpret_cast<u32*>(X)[j] = 0x3B003B00u;
    for (int j = tid; j < 17 * ROWEL2; j += 256) {
        const int row = j >> 4, col = j & 15;
        X[ONE2 + j] = (row == col) ? (u16)0x3F80 : (u16)0;
    }
    __syncthreads();

    const float tol_bf = bf2f(f2bf(1e-5f));
    uint4 nvP[4];

    for (int s = 1; s <= ITERS; ++s) {
        float dacc = 0.f;
        // ---- phase A: all reads, compute nv into regs ----
        #pragma unroll
        for (int k = 0; k < 4; ++k) if (k < nr) {
            const uint4 own = *reinterpret_cast<const uint4*>(Xc + r0b + (k << 12));
            const uint4 g0 = *reinterpret_cast<const uint4*>(Xc + offB[k][0]);
            const uint4 g1 = *reinterpret_cast<const uint4*>(Xc + offB[k][1]);
            const uint4 g2 = *reinterpret_cast<const uint4*>(Xc + offB[k][2]);
            uint4 nv;
            nv.x = stepElem(g0.x, g1.x, g2.x, own.x, dacc);
            nv.y = stepElem(g0.y, g1.y, g2.y, own.y, dacc);
            nv.z = stepElem(g0.z, g1.z, g2.z, own.z, dacc);
            nv.w = stepElem(g0.w, g1.w, g2.w, own.w, dacc);
            nvP[k] = nv;
        }
        #pragma unroll
        for (int off = 32; off > 0; off >>= 1) dacc += __shfl_down(dacc, off);
        if ((tid & 63) == 0) redL[tid >> 6] = dacc;
        __syncthreads();                      // reads done, redL ready

        if (tid == 0) {
            const float dtot = ((redL[0] + redL[1]) + redL[2]) + redL[3];
            __hip_atomic_store(&partials[(size_t)(s - 1) * NWG2 + wg], dtot,
                               __ATOMIC_RELEASE, __HIP_MEMORY_SCOPE_AGENT);
            __hip_atomic_store(&arrive[wg], (unsigned)s,
                               __ATOMIC_RELEASE, __HIP_MEMORY_SCOPE_AGENT);
        }

        if (wg == 0) {
            // barrier master + convergence checker (fused)
            unsigned guard = 0;
            for (;;) {
                int done = 1;
                #pragma unroll
                for (int j = 0; j < 8; ++j)
                    if (__hip_atomic_load(&arrive[(tid << 3) + j],
                            __ATOMIC_ACQUIRE, __HIP_MEMORY_SCOPE_AGENT)
                        != (unsigned)s) done = 0;
                if (done || ++guard > (1u << 21)) break;
                __builtin_amdgcn_s_sleep(1);
            }
            __syncthreads();
            int d = 0;
            if (tid < 64) {                   // lane = tree; EXACT findS math
                float t = 0.f;
                float* p = partials + (size_t)(s - 1) * NWG2 + (tid << 5);
                #pragma unroll
                for (int k2 = 0; k2 < 32; ++k2)
                    t += __hip_atomic_load(&p[k2], __ATOMIC_RELAXED,
                                           __HIP_MEMORY_SCOPE_AGENT);
                const float lnorm = bf2f(f2bf(t / 261120.0f));
                d = (__ballot(lnorm > tol_bf) == 0ULL) ? 1 : 0;
            }
            if (tid == 0)
                __hip_atomic_store(&gate[s], 1 | (d << 1),
                                   __ATOMIC_RELEASE, __HIP_MEMORY_SCOPE_AGENT);
        }

        if (tid == 0) {
            int g; unsigned guard = 0;
            for (;;) {
                g = __hip_atomic_load(&gate[s], __ATOMIC_ACQUIRE,
                                      __HIP_MEMORY_SCOPE_AGENT);
                if (g || ++guard > (1u << 22)) break;
                __builtin_amdgcn_s_sleep(1);
            }
            fbc = g >> 1;
        }
        __syncthreads();

        if (fbc || s == ITERS) break;         // X_S lives in nvP regs

        // ---- phase B: publish nv to LDS ----
        #pragma unroll
        for (int k = 0; k < 4; ++k) if (k < nr)
            *reinterpret_cast<uint4*>(Xc + r0b + (k << 12)) = nvP[k];
        __syncthreads();
    }

    // ---- fused output: d_out fp32 = [identity ; f32(X_S)] ----
    const int fb = sl * 16 + h * 8;
    #pragma unroll
    for (int k = 0; k < 4; ++k) {            // identity rows (all 512 covered)
        const int r = rg + (k << 7);
        float4 lo, hi;
        lo.x = (r == fb + 0) ? 1.f : 0.f;
        lo.y = (r == fb + 1) ? 1.f : 0.f;
        lo.z = (r == fb + 2) ? 1.f : 0.f;
        lo.w = (r == fb + 3) ? 1.f : 0.f;
        hi.x = (r == fb + 4) ? 1.f : 0.f;
        hi.y = (r == fb + 5) ? 1.f : 0.f;
        hi.z = (r == fb + 6) ? 1.f : 0.f;
        hi.w = (r == fb + 7) ? 1.f : 0.f;
        float* drow = out + ((size_t)b * TOTAL + r) * NTIPS + fb;
        *reinterpret_cast<float4*>(drow)     = lo;
        *reinterpret_cast<float4*>(drow + 4) = hi;
    }
    #pragma unroll
    for (int k = 0; k < 4; ++k) if (k < nr) { // X rows from nvP registers
        const int r = rg + (k << 7);
        float4 lo, hi;
        lo.x = bflo(nvP[k].x); lo.y = bfhi(nvP[k].x);
        lo.z = bflo(nvP[k].y); lo.w = bfhi(nvP[k].y);
        hi.x = bflo(nvP[k].z); hi.y = bfhi(nvP[k].z);
        hi.z = bflo(nvP[k].w); hi.w = bfhi(nvP[k].w);
        float* drow = out + ((size_t)b * TOTAL + NTIPS + r) * NTIPS + fb;
        *reinterpret_cast<float4*>(drow)     = lo;
        *reinterpret_cast<float4*>(drow + 4) = hi;
    }
}

// ===========================================================================
// R4 fallback path (proven): chunked multi-launch with per-step snapshots.
// ===========================================================================
__device__ __forceinline__ void barrier_lds_only() {
    __builtin_amdgcn_sched_barrier(0);
    asm volatile("s_waitcnt lgkmcnt(0)" ::: "memory");
    __builtin_amdgcn_s_barrier();
    __builtin_amdgcn_sched_barrier(0);
}

__device__ __forceinline__ void make_offsets(const int* __restrict__ edge,
        int b, int sl, int rg, int lbyte, int nr, u32 offB[4][3]) {
    #pragma unroll
    for (int k = 0; k < 4; ++k) if (k < nr) {
        const int i = rg + 128 * k;
        const int* ep = edge + ((size_t)b * TOTAL + NTIPS + i) * 3;
        #pragma unroll
        for (int t = 0; t < 3; ++t) {
            const int e = ep[t];
            u32 off;
            if (e >= NTIPS)          off = (u32)((e - NTIPS) * ROWEL);
            else if ((e >> 3) == sl) off = (u32)(ONEOFF + (e & 7) * ROWEL);
            else                     off = (u32)ZROW;
            offB[k][t] = off * 2u + (u32)lbyte;
        }
    }
}

__device__ __forceinline__ void init_const_rows(u16* X, int tid) {
    for (int j = tid; j < 9 * ROWEL; j += 256) {
        const int row = j >> 3, col = j & 7;
        const u16 v = (row == col) ? (u16)0x3F80 : (u16)0;
        X[ONEOFF + j] = v;
        X[BSTRIDE + ONEOFF + j] = v;
    }
}

template<int W, int MASK>
__global__ __launch_bounds__(256, 8) void chunk_kernel(
        const int* __restrict__ edge, float* __restrict__ partials,
        const int* __restrict__ ctrl, u16* __restrict__ slots, int q, int sBeg) {
    if (q >= 2 && ctrl[2] != 0) return;

    __shared__ u16 X[2 * BSTRIDE];
    __shared__ float redL[2][4];

    const int wg = blockIdx.x, b = wg >> 6, sl = wg & 63;
    const int tid = threadIdx.x, rg = tid >> 1;
    const int lbyte = (tid & 1) << 3;
    const int nr = (rg < 126) ? 4 : 3;
    char* Xc = reinterpret_cast<char*>(X);
    const u32 r0b = (u32)(rg * 16 + lbyte);

    u32 offB[4][3];
    make_offsets(edge, b, sl, rg, lbyte, nr, offB);

    u32 rowByte[4];
    #pragma unroll
    for (int k = 0; k < 4; ++k)
        rowByte[k] = (u32)wg * (u32)WGB + (u32)((rg + 128 * k) * 16) + (u32)lbyte;

    if (q == 1) {
        for (int j = tid; j < XSEC / 2; j += 256)
            reinterpret_cast<u32*>(X)[j] = 0x3B003B00u;
    } else {
        const char* src0 = reinterpret_cast<const char*>(slots)
                         + (size_t)((sBeg - 1) & MASK) * SLOTB;
        #pragma unroll
        for (int k = 0; k < 4; ++k) if (k < nr)
            *reinterpret_cast<uint2*>(Xc + r0b + (k << 11)) =
                *reinterpret_cast<const uint2*>(src0 + rowByte[k]);
    }
    init_const_rows(X, tid);

    f32x2 old01[4], old23[4];
    #pragma unroll
    for (int k = 0; k < 4; ++k) if (k < nr) {
        const uint2 ov = *reinterpret_cast<const uint2*>(Xc + r0b + (k << 11));
        old01[k] = unpk(ov.x); old23[k] = unpk(ov.y);
    }
    __syncthreads();

    #pragma unroll
    for (int u = 0; u < W; ++u) {
        const int s = sBeg + u;
        const int srcB = (u & 1) ? BUFB : 0;
        const int dstB = ((u + 1) & 1) ? BUFB : 0;
        char* slotC = reinterpret_cast<char*>(slots) + (size_t)(s & MASK) * SLOTB;
        float dacc = 0.f;
        #pragma unroll
        for (int k = 0; k < 4; ++k) if (k < nr) {
            const uint2 g0 = *reinterpret_cast<const uint2*>(Xc + offB[k][0] + srcB);
            const uint2 g1 = *reinterpret_cast<const uint2*>(Xc + offB[k][1] + srcB);
            const uint2 g2 = *reinterpret_cast<const uint2*>(Xc + offB[k][2] + srcB);
            const f32x2 a01 = (unpk(g0.x) + unpk(g1.x)) + unpk(g2.x);
            const f32x2 a23 = (unpk(g0.y) + unpk(g1.y)) + unpk(g2.y);
            const f32x2 q01 = div3v(a01), q23 = div3v(a23);
            uint2 nv;
            nv.x = pkbf(q01.x, q01.y);
            nv.y = pkbf(q23.x, q23.y);
            *reinterpret_cast<uint2*>(Xc + r0b + ((k << 11) + dstB)) = nv;
            *reinterpret_cast<uint2*>(slotC + rowByte[k]) = nv;
            const f32x2 n01 = unpk(nv.x), n23 = unpk(nv.y);
            const f32x2 d01v = n01 - old01[k];
            const f32x2 d23v = n23 - old23[k];
            const u32 d01 = pkbf(d01v.x, d01v.y);
            const u32 d23 = pkbf(d23v.x, d23v.y);
            dacc += fabsf(bflo(d01));
            dacc += fabsf(bfhi(d01));
            dacc += fabsf(bflo(d23));
            dacc += fabsf(bfhi(d23));
            old01[k] = n01; old23[k] = n23;
        }
        #pragma unroll
        for (int off = 32; off > 0; off >>= 1) dacc += __shfl_down(dacc, off);
        if ((tid & 63) == 0) redL[u & 1][tid >> 6] = dacc;
        barrier_lds_only();
        if (tid == 0) {
            const float dtot = ((redL[u & 1][0] + redL[u & 1][1])
                                + redL[u & 1][2]) + redL[u & 1][3];
            partials[((size_t)(s - 1) * BS + b) * NSLAB + sl] = dtot;
        }
    }
}

__global__ void findS_kernel(const float* __restrict__ partials,
                             int* __restrict__ ctrl, int smax) {
    if (ctrl[2] != 0) return;
    const int lane = threadIdx.x;
    const float tol_bf = bf2f(f2bf(1e-5f));
    int S = -1;
    for (int s = 1; s <= smax; ++s) {
        const float* p = partials + ((size_t)(s - 1) * BS + lane) * NSLAB;
        float t = 0.f;
        #pragma unroll
        for (int k = 0; k < NSLAB; ++k) t += p[k];
        const float lnorm = bf2f(f2bf(t / 261120.0f));
        if (__ballot(lnorm > tol_bf) == 0ULL) { S = s; break; }
    }
    if (S < 0 && smax == ITERS) S = ITERS;
    if (lane == 0 && S > 0) { ctrl[0] = S; ctrl[2] = 1; }
}

__global__ __launch_bounds__(256) void copyfinal_kernel(
        const int* __restrict__ ctrl, const u16* __restrict__ slots,
        u16* __restrict__ finalX) {
    const int S = ctrl[0];
    const uint4* src = reinterpret_cast<const uint4*>(slots + (size_t)(S & 3) * XB);
    uint4* dst = reinterpret_cast<uint4*>(finalX);
    const size_t n = XB / 8;
    for (size_t i = (size_t)blockIdx.x * 256 + threadIdx.x; i < n;
         i += (size_t)gridDim.x * 256)
        dst[i] = src[i];
}

__global__ __launch_bounds__(64) void convert_kernel(
        const u16* __restrict__ base, const int* __restrict__ ctrl, int mask,
        float* __restrict__ out) {
    const int r = blockIdx.x;
    const int b = blockIdx.y;
    const int f0 = threadIdx.x << 3;
    float4 lo, hi;
    if (r < NTIPS) {
        lo.x = (r == f0 + 0) ? 1.f : 0.f;
        lo.y = (r == f0 + 1) ? 1.f : 0.f;
        lo.z = (r == f0 + 2) ? 1.f : 0.f;
        lo.w = (r == f0 + 3) ? 1.f : 0.f;
        hi.x = (r == f0 + 4) ? 1.f : 0.f;
        hi.y = (r == f0 + 5) ? 1.f : 0.f;
        hi.z = (r == f0 + 6) ? 1.f : 0.f;
        hi.w = (r == f0 + 7) ? 1.f : 0.f;
    } else {
        const u16* src = base + (mask >= 0 ? (size_t)(ctrl[0] & mask) * XB
                                           : (size_t)0);
        const u16* row = src + (((size_t)b * NSLAB + threadIdx.x) * DIM
                                + (r - NTIPS)) * ROWEL;
        const ushort4 a = *reinterpret_cast<const ushort4*>(row);
        const ushort4 c = *reinterpret_cast<const ushort4*>(row + 4);
        lo.x = bf2f(a.x); lo.y = bf2f(a.y); lo.z = bf2f(a.z); lo.w = bf2f(a.w);
        hi.x = bf2f(c.x); hi.y = bf2f(c.y); hi.z = bf2f(c.z); hi.w = bf2f(c.w);
    }
    float* drow = out + ((size_t)b * TOTAL + r) * NTIPS + f0;
    *reinterpret_cast<float4*>(drow)     = lo;
    *reinterpret_cast<float4*>(drow + 4) = hi;
}

extern "C" void kernel_launch(void* const* d_in, const int* in_sizes, int n_in,
                              void* d_out, int out_size, void* d_ws, size_t ws_size,
                              hipStream_t stream) {
    const int* edge = (const int*)d_in[1];
    float* out = (float*)d_out;

    // ---- persistent-path precheck: guaranteed co-residency of 2048 WGs ----
    static int coop = -1;
    if (coop < 0) {
        int dev = 0; hipGetDevice(&dev);
        int ncu = 0;
        hipDeviceGetAttribute(&ncu, hipDeviceAttributeMultiprocessorCount, dev);
        int nb = 0;
        hipError_t e = hipOccupancyMaxActiveBlocksPerMultiprocessor(
                           &nb, persist_kernel, 256, 0);
        coop = (e == hipSuccess && ncu > 0 &&
                (long long)ncu * nb >= (long long)NWG2) ? 1 : 0;
    }
    const size_t persistB = (size_t)(NWG2 + 64) * 4 + NPART2 * 4;

    if (coop && ws_size >= persistB) {
        unsigned* arrive = (unsigned*)d_ws;
        int*      gate   = (int*)(arrive + NWG2);
        float*  partials = (float*)(gate + 64);
        hipMemsetAsync(d_ws, 0, (size_t)(NWG2 + 64) * 4, stream);
        persist_kernel<<<NWG2, 256, 0, stream>>>(edge, partials, arrive,
                                                 gate, out);
        return;
    }

    // ---- R4 fallback ----
    const size_t partB = NPART * sizeof(float);
    if (ws_size >= 8 * SLOTB + partB + 256) {
        u16*   slots    = (u16*)d_ws;
        float* partials = (float*)((char*)d_ws + 8 * SLOTB);
        int*   ctrl     = (int*)((char*)partials + partB);
        hipMemsetAsync(ctrl, 0, 4 * sizeof(int), stream);
        for (int q = 1; q <= 3; ++q) {
            chunk_kernel<4, 7><<<NWG, 256, 0, stream>>>(edge, partials, ctrl,
                                                        slots, q, 4 * q - 3);
            findS_kernel<<<1, 64, 0, stream>>>(partials, ctrl, 4 * q);
        }
        for (int q = 4; q <= 7; ++q) {
            chunk_kernel<8, 7><<<NWG, 256, 0, stream>>>(edge, partials, ctrl,
                                                        slots, q,
                                                        13 + 8 * (q - 4));
            findS_kernel<<<1, 64, 0, stream>>>(partials, ctrl, 20 + 8 * (q - 4));
        }
        chunk_kernel<6, 7><<<NWG, 256, 0, stream>>>(edge, partials, ctrl,
                                                    slots, 8, 45);
        findS_kernel<<<1, 64, 0, stream>>>(partials, ctrl, 50);
        convert_kernel<<<dim3(TOTAL, BS), 64, 0, stream>>>(slots, ctrl, 7, out);
    } else if (ws_size >= 4 * SLOTB + partB + 256) {
        u16*   slots    = (u16*)d_ws;
        float* partials = (float*)((char*)d_ws + 4 * SLOTB);
        int*   ctrl     = (int*)((char*)partials + partB);
        hipMemsetAsync(ctrl, 0, 4 * sizeof(int), stream);
        for (int q = 1; q <= 12; ++q) {
            chunk_kernel<4, 3><<<NWG, 256, 0, stream>>>(edge, partials, ctrl,
                                                        slots, q, 4 * q - 3);
            findS_kernel<<<1, 64, 0, stream>>>(partials, ctrl, 4 * q);
        }
        chunk_kernel<2, 3><<<NWG, 256, 0, stream>>>(edge, partials, ctrl,
                                                    slots, 13, 49);
        findS_kernel<<<1, 64, 0, stream>>>(partials, ctrl, 50);
        convert_kernel<<<dim3(TOTAL, BS), 64, 0, stream>>>(slots, ctrl, 3, out);
    } else {
        u16*   slots    = (u16*)d_out;
        u16*   finalX   = (u16*)d_ws;
        float* partials = (float*)((char*)d_ws + SLOTB);
        int*   ctrl     = (int*)((char*)partials + partB);
        hipMemsetAsync(ctrl, 0, 4 * sizeof(int), stream);
        for (int q = 1; q <= 12; ++q) {
            chunk_kernel<4, 3><<<NWG, 256, 0, stream>>>(edge, partials, ctrl,
                                                        slots, q, 4 * q - 3);
            findS_kernel<<<1, 64, 0, stream>>>(partials, ctrl, 4 * q);
        }
        chunk_kernel<2, 3><<<NWG, 256, 0, stream>>>(edge, partials, ctrl,
                                                    slots, 13, 49);
        findS_kernel<<<1, 64, 0, stream>>>(partials, ctrl, 50);
        copyfinal_kernel<<<2048, 256, 0, stream>>>(ctrl, slots, finalX);
        convert_kernel<<<dim3(TOTAL, BS), 64, 0, stream>>>(finalX, ctrl, -1, out);
    }
}